// Round 11
// baseline (245.467 us; speedup 1.0000x reference)
//
#include <hip/hip_runtime.h>
#include <hip/hip_cooperative_groups.h>
#include <math.h>

namespace cg = cooperative_groups;

#define BQ   4
#define QN   256
#define KN   1024
#define DIN  256     // Q_SIZE == K_SIZE == V_SIZE
#define HD   128     // H

// C2 = 2*log2(e): exp2(C2*x) = e^{2x}
#define C2F   2.8853900817779268f
#define NL2E  (-2.8853900817779268f)

union SMem {
    struct { float xT[32][18]; float WT[32][136]; } p;            // proj   ~19.7 KB
    struct { float red[4][4]; } a;                                // score  tiny
    struct { float aT[32][36]; float v[32][36];
             float red[4][32][36]; } b;                           // av     ~27.6 KB
};

// ---------------------------------------------------------------------------
// ONE cooperative kernel, grid = 256 blocks x 256 threads (1 block/CU).
// Phase 0: projections (R8-verified tiled GEMM) -> Eq, EkT4 in exp2 domain.
// Phase A: block = (b, 4 q-rows) x full k.  Whole softmax row in-block:
//          e normalized in registers, ONE write to attn.  No partial buffer.
// Phase B: R9-verified 32x32 register-prefetched AV GEMM (attn already
//          normalized).  grid.sync() between phases replaces 2 launches.
// ---------------------------------------------------------------------------
__global__ __launch_bounds__(256, 2) void mono_kernel(const float* __restrict__ queries,
                                                      const float* __restrict__ keys,
                                                      const float* __restrict__ values,
                                                      const int* __restrict__ valid_lens,
                                                      const float* __restrict__ W_q,
                                                      const float* __restrict__ W_k,
                                                      const float* __restrict__ w_v,
                                                      float* __restrict__ Eq,
                                                      float* __restrict__ EkT4,
                                                      float* __restrict__ attn,
                                                      float* __restrict__ out) {
    cg::grid_group grid = cg::this_grid();
    __shared__ SMem sm;

    const int bid = blockIdx.x;
    const int t = threadIdx.x;

    // ===================== Phase 0: projections =====================
    for (int tile = bid; tile < (BQ * QN + BQ * KN) / 16; tile += 256) {
        const int row0 = tile * 16;
        const bool is_q = row0 < BQ * QN;
        const float* x = is_q ? queries : keys;
        const float* W = is_q ? W_q : W_k;
        const int xr0 = is_q ? row0 : row0 - BQ * QN;

        const int h0 = (t & 31) * 4;
        const int r0 = (t >> 5) * 2;

        float acc[2][4];
#pragma unroll
        for (int r = 0; r < 2; r++)
#pragma unroll
            for (int c = 0; c < 4; c++) acc[r][c] = 0.f;

        for (int ks = 0; ks < DIN; ks += 32) {
            __syncthreads();
            if (t < 128) {
                const int r = t >> 3, k4 = (t & 7) * 4;
                float4 xv = *(const float4*)(x + (size_t)(xr0 + r) * DIN + ks + k4);
                sm.p.xT[k4 + 0][r] = xv.x; sm.p.xT[k4 + 1][r] = xv.y;
                sm.p.xT[k4 + 2][r] = xv.z; sm.p.xT[k4 + 3][r] = xv.w;
            }
#pragma unroll
            for (int u = 0; u < 4; u++) {
                const int h = (t >> 3) + 32 * u, k4 = (t & 7) * 4;
                float4 wv = *(const float4*)(W + (size_t)h * DIN + ks + k4);
                sm.p.WT[k4 + 0][h] = wv.x; sm.p.WT[k4 + 1][h] = wv.y;
                sm.p.WT[k4 + 2][h] = wv.z; sm.p.WT[k4 + 3][h] = wv.w;
            }
            __syncthreads();
#pragma unroll
            for (int kk = 0; kk < 32; kk++) {
                float2 xv = *(const float2*)&sm.p.xT[kk][r0];
                float4 wv = *(const float4*)&sm.p.WT[kk][h0];
                const float xr[2] = {xv.x, xv.y};
                const float wc[4] = {wv.x, wv.y, wv.z, wv.w};
#pragma unroll
                for (int r = 0; r < 2; r++)
#pragma unroll
                    for (int c = 0; c < 4; c++)
                        acc[r][c] = __builtin_fmaf(xr[r], wc[c], acc[r][c]);
            }
        }

        if (is_q) {
#pragma unroll
            for (int r = 0; r < 2; r++) {
                float4 o;
                o.x = __builtin_amdgcn_exp2f(C2F * acc[r][0]);
                o.y = __builtin_amdgcn_exp2f(C2F * acc[r][1]);
                o.z = __builtin_amdgcn_exp2f(C2F * acc[r][2]);
                o.w = __builtin_amdgcn_exp2f(C2F * acc[r][3]);
                *(float4*)(Eq + (size_t)(row0 + r0 + r) * HD + h0) = o;
            }
        } else {
            const int krow = row0 - BQ * QN;
            const int b = krow >> 10, k0 = (krow & (KN - 1)) + r0;
            const int h4 = t & 31;
#pragma unroll
            for (int r = 0; r < 2; r++) {
                float4 o;
                o.x = __builtin_amdgcn_exp2f(C2F * acc[r][0]);
                o.y = __builtin_amdgcn_exp2f(C2F * acc[r][1]);
                o.z = __builtin_amdgcn_exp2f(C2F * acc[r][2]);
                o.w = __builtin_amdgcn_exp2f(C2F * acc[r][3]);
                *(float4*)(EkT4 + ((size_t)(b * 32 + h4) * KN + k0 + r) * 4) = o;
            }
        }
        __syncthreads();
    }

    __threadfence();
    grid.sync();

    // ===================== Phase A: scores + in-block softmax =====================
    {
        const int b = bid & 3;
        const int q0 = (bid >> 2) * 4;          // 64 q-tiles of 4
        const int valid = valid_lens[b];
        const int row = b * QN + q0;

        float ev[4][4];                         // [s][q]
        float rs[4] = {0.f, 0.f, 0.f, 0.f};
        const float4* ekbase = (const float4*)EkT4 + (size_t)(b * 32) * KN;

#pragma unroll
        for (int s = 0; s < 4; s++) {
            const int k = s * 256 + t;
            if (s * 256 < valid) {
                float a[4] = {0.f, 0.f, 0.f, 0.f};
                const float4* kcol = ekbase + k;
#pragma unroll 4
                for (int i = 0; i < 32; i++) {
                    float4 ek4 = kcol[(size_t)i * KN];
                    float4 w4 = *(const float4*)(w_v + i * 4);              // uniform
                    const float ekv[4] = {ek4.x, ek4.y, ek4.z, ek4.w};
                    const float wv4[4] = {w4.x, w4.y, w4.z, w4.w};
#pragma unroll
                    for (int q = 0; q < 4; q++) {
                        float4 e4 = *(const float4*)(Eq + (size_t)(row + q) * HD + i * 4);  // uniform
                        a[q] = __builtin_fmaf(wv4[0],
                               __builtin_amdgcn_rcpf(__builtin_fmaf(ekv[0], e4.x, 1.0f)), a[q]);
                        a[q] = __builtin_fmaf(wv4[1],
                               __builtin_amdgcn_rcpf(__builtin_fmaf(ekv[1], e4.y, 1.0f)), a[q]);
                        a[q] = __builtin_fmaf(wv4[2],
                               __builtin_amdgcn_rcpf(__builtin_fmaf(ekv[2], e4.z, 1.0f)), a[q]);
                        a[q] = __builtin_fmaf(wv4[3],
                               __builtin_amdgcn_rcpf(__builtin_fmaf(ekv[3], e4.w, 1.0f)), a[q]);
                    }
                }
#pragma unroll
                for (int q = 0; q < 4; q++) {
                    ev[s][q] = (k < valid) ? __builtin_amdgcn_exp2f(NL2E * a[q]) : 0.f;
                    rs[q] += ev[s][q];
                }
            } else {
#pragma unroll
                for (int q = 0; q < 4; q++) ev[s][q] = 0.f;
            }
        }

        // block-wide row sums
#pragma unroll
        for (int off = 32; off > 0; off >>= 1)
#pragma unroll
            for (int q = 0; q < 4; q++) rs[q] += __shfl_xor(rs[q], off, 64);
        const int wv_ = t >> 6;
        __syncthreads();
        if ((t & 63) == 0) {
#pragma unroll
            for (int q = 0; q < 4; q++) sm.a.red[wv_][q] = rs[q];
        }
        __syncthreads();
        float inv[4];
#pragma unroll
        for (int q = 0; q < 4; q++)
            inv[q] = 1.0f / (sm.a.red[0][q] + sm.a.red[1][q] + sm.a.red[2][q] + sm.a.red[3][q]);

        // normalized e -> attn (coalesced)
#pragma unroll
        for (int s = 0; s < 4; s++)
#pragma unroll
            for (int q = 0; q < 4; q++)
                attn[(size_t)(row + q) * KN + s * 256 + t] = ev[s][q] * inv[q];
    }

    __threadfence();
    grid.sync();

    // ===================== Phase B: out = attn @ values =====================
    {
        const int b = bid & 3;
        const int qt = (bid >> 2) & 7;
        const int vt = bid >> 5;
        const int q0 = qt * 32, v0 = vt * 32;
        const int valid = valid_lens[b];
        const int T = (valid + 31) >> 5;

        const int sr = t >> 3, sc = (t & 7) * 4;
        const float* abase = attn + (size_t)(b * QN + q0 + sr) * KN + sc;
        const float* vbase = values + ((size_t)b * KN + sr) * DIN + v0 + sc;

        const int vh = t & 7, qh = (t >> 3) & 7, ks = t >> 6;

        float acc[4][4];
#pragma unroll
        for (int r = 0; r < 4; r++)
#pragma unroll
            for (int c = 0; c < 4; c++) acc[r][c] = 0.f;

        float4 ra = *(const float4*)abase;      // prefetch tile 0
        float4 rv = *(const float4*)vbase;

        for (int tile = 0; tile < T; tile++) {
            __syncthreads();
            sm.b.aT[sc + 0][sr] = ra.x;
            sm.b.aT[sc + 1][sr] = ra.y;
            sm.b.aT[sc + 2][sr] = ra.z;
            sm.b.aT[sc + 3][sr] = ra.w;
            *(float4*)&sm.b.v[sr][sc] = rv;
            __syncthreads();
            if (tile + 1 < T) {
                ra = *(const float4*)(abase + (tile + 1) * 32);
                rv = *(const float4*)(vbase + (size_t)(tile + 1) * 32 * DIN);
            }
#pragma unroll
            for (int i = 0; i < 8; i++) {
                const int kk = ks * 8 + i;
                float4 aq = *(const float4*)&sm.b.aT[kk][qh * 4];
                float4 vv = *(const float4*)&sm.b.v[kk][vh * 4];
                const float ar[4] = {aq.x, aq.y, aq.z, aq.w};
                const float vc[4] = {vv.x, vv.y, vv.z, vv.w};
#pragma unroll
                for (int r = 0; r < 4; r++)
#pragma unroll
                    for (int c = 0; c < 4; c++)
                        acc[r][c] = __builtin_fmaf(ar[r], vc[c], acc[r][c]);
            }
        }

        __syncthreads();
#pragma unroll
        for (int r = 0; r < 4; r++)
            *(float4*)&sm.b.red[ks][qh * 4 + r][vh * 4] =
                make_float4(acc[r][0], acc[r][1], acc[r][2], acc[r][3]);
        __syncthreads();

        const int q = t >> 3, v4 = (t & 7) * 4;
        float4 r0 = *(const float4*)&sm.b.red[0][q][v4];
        float4 r1 = *(const float4*)&sm.b.red[1][q][v4];
        float4 r2 = *(const float4*)&sm.b.red[2][q][v4];
        float4 r3 = *(const float4*)&sm.b.red[3][q][v4];
        float4 o;
        o.x = r0.x + r1.x + r2.x + r3.x;
        o.y = r0.y + r1.y + r2.y + r3.y;
        o.z = r0.z + r1.z + r2.z + r3.z;
        o.w = r0.w + r1.w + r2.w + r3.w;
        *(float4*)(out + (size_t)(b * QN + q0 + q) * DIN + v0 + v4) = o;
    }
}

extern "C" void kernel_launch(void* const* d_in, const int* in_sizes, int n_in,
                              void* d_out, int out_size, void* d_ws, size_t ws_size,
                              hipStream_t stream) {
    const float* queries    = (const float*)d_in[0];
    const float* keys       = (const float*)d_in[1];
    const float* values     = (const float*)d_in[2];
    const int*   valid_lens = (const int*)d_in[3];
    const float* W_q        = (const float*)d_in[4];
    const float* W_k        = (const float*)d_in[5];
    const float* w_v        = (const float*)d_in[6];
    float* out = (float*)d_out;

    float* Eq   = (float*)d_ws;                    // [B*QN][HD]     512 KB
    float* EkT4 = Eq + (size_t)BQ * QN * HD;       // [B][32][KN][4]   2 MB
    float* attn = EkT4 + (size_t)BQ * HD * KN;     // [B*QN][KN]       4 MB (normalized)

    void* args[] = {(void*)&queries, (void*)&keys, (void*)&values, (void*)&valid_lens,
                    (void*)&W_q, (void*)&W_k, (void*)&w_v,
                    (void*)&Eq, (void*)&EkT4, (void*)&attn, (void*)&out};
    hipLaunchCooperativeKernel((const void*)mono_kernel, dim3(256), dim3(256),
                               args, 0, stream);
}

// Round 12
// 112.344 us; speedup vs baseline: 2.1850x; 2.1850x over previous
//
#include <hip/hip_runtime.h>
#include <math.h>

#define BQ   4
#define QN   256
#define KN   1024
#define DIN  256     // Q_SIZE == K_SIZE == V_SIZE
#define HD   128     // H

// C2 = 2*log2(e): exp2(C2*x) = e^{2x}
#define C2F   2.8853900817779268f
#define NL2E  (-2.8853900817779268f)

// ---------------------------------------------------------------------------
// Kernel 1: projections as tiled GEMM, outputs in EXP2 DOMAIN (verified R8):
//   Eq  [b*QN+q][h]    = exp2(C2*qp)
//   EkT4[b][h/4][k][4] = exp2(C2*kp)   (4 consecutive h per float4)
// ---------------------------------------------------------------------------
__global__ __launch_bounds__(256, 2) void proj_kernel(const float* __restrict__ queries,
                                                      const float* __restrict__ keys,
                                                      const float* __restrict__ W_q,
                                                      const float* __restrict__ W_k,
                                                      float* __restrict__ Eq,
                                                      float* __restrict__ EkT4) {
    __shared__ float xT[32][18];    // [k][row], 16 rows + pad
    __shared__ float WT[32][136];   // [k][h]

    const int t = threadIdx.x;
    const int row0 = blockIdx.x * 16;
    const bool is_q = row0 < BQ * QN;
    const float* x = is_q ? queries : keys;
    const float* W = is_q ? W_q : W_k;
    const int xr0 = is_q ? row0 : row0 - BQ * QN;

    const int h0 = (t & 31) * 4;        // 4 h columns
    const int r0 = (t >> 5) * 2;        // 2 rows

    float acc[2][4];
#pragma unroll
    for (int r = 0; r < 2; r++)
#pragma unroll
        for (int c = 0; c < 4; c++) acc[r][c] = 0.f;

    for (int ks = 0; ks < DIN; ks += 32) {
        __syncthreads();
        if (t < 128) {   // x[16 rows][32 k] -> xT[k][row]
            const int r = t >> 3, k4 = (t & 7) * 4;
            float4 xv = *(const float4*)(x + (size_t)(xr0 + r) * DIN + ks + k4);
            xT[k4 + 0][r] = xv.x; xT[k4 + 1][r] = xv.y;
            xT[k4 + 2][r] = xv.z; xT[k4 + 3][r] = xv.w;
        }
#pragma unroll
        for (int u = 0; u < 4; u++) {   // W[128 h][32 k] -> WT[k][h]
            const int h = (t >> 3) + 32 * u, k4 = (t & 7) * 4;
            float4 wv = *(const float4*)(W + (size_t)h * DIN + ks + k4);
            WT[k4 + 0][h] = wv.x; WT[k4 + 1][h] = wv.y;
            WT[k4 + 2][h] = wv.z; WT[k4 + 3][h] = wv.w;
        }
        __syncthreads();
#pragma unroll
        for (int kk = 0; kk < 32; kk++) {
            float2 xv = *(const float2*)&xT[kk][r0];
            float4 wv = *(const float4*)&WT[kk][h0];
            const float xr[2] = {xv.x, xv.y};
            const float wc[4] = {wv.x, wv.y, wv.z, wv.w};
#pragma unroll
            for (int r = 0; r < 2; r++)
#pragma unroll
                for (int c = 0; c < 4; c++)
                    acc[r][c] = __builtin_fmaf(xr[r], wc[c], acc[r][c]);
        }
    }

    if (is_q) {
#pragma unroll
        for (int r = 0; r < 2; r++) {
            float4 o;
            o.x = __builtin_amdgcn_exp2f(C2F * acc[r][0]);
            o.y = __builtin_amdgcn_exp2f(C2F * acc[r][1]);
            o.z = __builtin_amdgcn_exp2f(C2F * acc[r][2]);
            o.w = __builtin_amdgcn_exp2f(C2F * acc[r][3]);
            *(float4*)(Eq + (size_t)(row0 + r0 + r) * HD + h0) = o;
        }
    } else {
        const int krow = row0 - BQ * QN;
        const int b = krow >> 10, k0 = (krow & (KN - 1)) + r0;
        const int h4 = t & 31;                      // = h0/4
#pragma unroll
        for (int r = 0; r < 2; r++) {
            float4 o;
            o.x = __builtin_amdgcn_exp2f(C2F * acc[r][0]);
            o.y = __builtin_amdgcn_exp2f(C2F * acc[r][1]);
            o.z = __builtin_amdgcn_exp2f(C2F * acc[r][2]);
            o.w = __builtin_amdgcn_exp2f(C2F * acc[r][3]);
            *(float4*)(EkT4 + ((size_t)(b * 32 + h4) * KN + k0 + r) * 4) = o;
        }
    }
}

// ---------------------------------------------------------------------------
// Kernel 2: scores -> unnormalized e + per-chunk row sums (verified R9).
// Grid = 4b x 32 q-tiles(8) x 8 k-chunks(128) = 1024 blocks (4 blocks/CU).
// ---------------------------------------------------------------------------
__global__ __launch_bounds__(256, 4) void score_kernel(const float* __restrict__ Eq,
                                                       const float* __restrict__ EkT4,
                                                       const int* __restrict__ valid_lens,
                                                       const float* __restrict__ w_v,
                                                       float* __restrict__ attn,
                                                       float* __restrict__ partial) {
    __shared__ float s_w[HD];
    __shared__ float s_pq[HD][8];
    __shared__ float s_part[2][8][128];
    __shared__ float s_red[4][4];

    const int blk = blockIdx.x;
    const int b = blk & 3;
    const int q0 = ((blk >> 2) & 31) * 8;
    const int c = blk >> 7;            // 0..7
    const int t = threadIdx.x;
    const int valid = valid_lens[b];
    float* pp = partial + (size_t)(b * QN + q0) * 8;

    if (c * 128 >= valid) {            // fully masked chunk: attn never read here
        if (t < 8) pp[t * 8 + c] = 0.f;
        return;
    }

    const int kl = t & 127;
    const int hh = t >> 7;
    const int k = c * 128 + kl;

    if (t < HD) s_w[t] = w_v[t];
    {
        const int h = t & 127;
#pragma unroll
        for (int j = 0; j < 4; j++) {
            const int q = (t >> 7) * 4 + j;
            s_pq[h][q] = Eq[(size_t)(b * QN + q0 + q) * HD + h];
        }
    }
    __syncthreads();

    // 4 h per dwordx4: quad index = b*32 + hh*16 + i
    const float4* kcol = (const float4*)EkT4 + ((size_t)(b * 32 + hh * 16) * KN + k);
    float acc[8] = {0.f, 0.f, 0.f, 0.f, 0.f, 0.f, 0.f, 0.f};

#pragma unroll 4
    for (int i = 0; i < 16; i++) {
        float4 ek4 = kcol[(size_t)i * KN];
        const int hb = hh * 64 + i * 4;
        const float ekv[4] = {ek4.x, ek4.y, ek4.z, ek4.w};
#pragma unroll
        for (int j = 0; j < 4; j++) {
            const float ek = ekv[j];
            const float w = s_w[hb + j];
            float4 p0 = *(const float4*)&s_pq[hb + j][0];
            float4 p1 = *(const float4*)&s_pq[hb + j][4];
            acc[0] = __builtin_fmaf(w, __builtin_amdgcn_rcpf(__builtin_fmaf(ek, p0.x, 1.0f)), acc[0]);
            acc[1] = __builtin_fmaf(w, __builtin_amdgcn_rcpf(__builtin_fmaf(ek, p0.y, 1.0f)), acc[1]);
            acc[2] = __builtin_fmaf(w, __builtin_amdgcn_rcpf(__builtin_fmaf(ek, p0.z, 1.0f)), acc[2]);
            acc[3] = __builtin_fmaf(w, __builtin_amdgcn_rcpf(__builtin_fmaf(ek, p0.w, 1.0f)), acc[3]);
            acc[4] = __builtin_fmaf(w, __builtin_amdgcn_rcpf(__builtin_fmaf(ek, p1.x, 1.0f)), acc[4]);
            acc[5] = __builtin_fmaf(w, __builtin_amdgcn_rcpf(__builtin_fmaf(ek, p1.y, 1.0f)), acc[5]);
            acc[6] = __builtin_fmaf(w, __builtin_amdgcn_rcpf(__builtin_fmaf(ek, p1.z, 1.0f)), acc[6]);
            acc[7] = __builtin_fmaf(w, __builtin_amdgcn_rcpf(__builtin_fmaf(ek, p1.w, 1.0f)), acc[7]);
        }
    }

#pragma unroll
    for (int q = 0; q < 8; q++) s_part[hh][q][kl] = acc[q];
    __syncthreads();

    const int qb = (t >> 7) * 4;
    float* arow = attn + (size_t)(b * QN + q0 + qb) * KN + k;
    float psum[4];
#pragma unroll
    for (int j = 0; j < 4; j++) {
        const int q = qb + j;
        float tot = s_part[0][q][kl] + s_part[1][q][kl];
        float e = (k < valid) ? __builtin_amdgcn_exp2f(NL2E * tot) : 0.f;
        arow[(size_t)j * KN] = e;
#pragma unroll
        for (int off = 32; off > 0; off >>= 1) e += __shfl_xor(e, off, 64);
        psum[j] = e;
    }
    const int wv = t >> 6;
    if ((t & 63) == 0) {
#pragma unroll
        for (int j = 0; j < 4; j++) s_red[wv][j] = psum[j];
    }
    __syncthreads();
    if (t < 8) {
        const int q = t;
        float s = (q < 4) ? (s_red[0][q] + s_red[1][q])
                          : (s_red[2][q - 4] + s_red[3][q - 4]);
        pp[q * 8 + c] = s;
    }
}

// ---------------------------------------------------------------------------
// Kernel 3: out = normalize(e) @ values, register-prefetched tiled GEMM.
// R12: tile 16q x 32v -> grid = 4b x 16qt x 8vt = 512 blocks (2 blocks/CU,
// was 1); k-slices of 4 x 8 slices (8 fma per ds_read, same as R9); s_red
// re-laid out [8][16][37] so slice stride = 592 ≡ 16 (mod 32) banks, row
// stride 37 ≡ 5 — kills the all-slices-on-bank-0 conflict seen in R11.
// ---------------------------------------------------------------------------
__global__ __launch_bounds__(256, 2) void av_kernel(const float* __restrict__ attn,
                                                    const float* __restrict__ partial,
                                                    const float* __restrict__ values,
                                                    const int* __restrict__ valid_lens,
                                                    float* __restrict__ out) {
    __shared__ float s_aT[32][20];      // [kk][q], 16 q + pad
    __shared__ float s_v[32][36];       // [kk][v]
    __shared__ float s_red[8][16][37];  // per-k-slice partials, conflict-padded
    __shared__ float s_inv[16];

    const int blk = blockIdx.x;
    const int b = blk & 3;
    const int qt = (blk >> 2) & 15;
    const int vt = blk >> 6;
    const int t = threadIdx.x;
    const int q0 = qt * 16, v0 = vt * 32;
    const int valid = valid_lens[b];
    const int T = (valid + 31) >> 5;    // k-tiles (valid >= 1 so T >= 1)

    if (t < 16) {
        const float* pr = partial + (size_t)(b * QN + q0 + t) * 8;
        float4 pA = *(const float4*)pr;
        float4 pB = *(const float4*)(pr + 4);
        s_inv[t] = 1.0f / (pA.x + pA.y + pA.z + pA.w + pB.x + pB.y + pB.z + pB.w);
    }

    // staging: t<128 loads attn[q0 + (t>>3)][kt + (t&7)*4 ..+3] (transposed);
    //          all 256 load V[kt + (t>>3)][v0 + (t&7)*4 ..+3]
    const int sr = t >> 3, sc = (t & 7) * 4;
    const float* abase = attn + (size_t)(b * QN + q0 + (sr & 15)) * KN + sc;
    const float* vbase = values + ((size_t)b * KN + sr) * DIN + v0 + sc;

    const int ks = t >> 5;              // 8 k-slices of 4
    const int qh = (t >> 3) & 3;        // 4 q-groups of 4
    const int vh = t & 7;               // 8 v-groups of 4

    float acc[4][4];
#pragma unroll
    for (int r = 0; r < 4; r++)
#pragma unroll
        for (int c = 0; c < 4; c++) acc[r][c] = 0.f;

    float4 ra = *(const float4*)abase;      // prefetch tile 0
    float4 rv = *(const float4*)vbase;

    for (int tile = 0; tile < T; tile++) {
        __syncthreads();
        if (t < 128) {
            s_aT[sc + 0][sr] = ra.x;        // attn transposed -> [kk][q]
            s_aT[sc + 1][sr] = ra.y;
            s_aT[sc + 2][sr] = ra.z;
            s_aT[sc + 3][sr] = ra.w;
        }
        *(float4*)&s_v[sr][sc] = rv;
        __syncthreads();
        if (tile + 1 < T) {                 // issue next tile's loads now
            ra = *(const float4*)(abase + (tile + 1) * 32);
            rv = *(const float4*)(vbase + (size_t)(tile + 1) * 32 * DIN);
        }
#pragma unroll
        for (int i = 0; i < 4; i++) {
            const int kk = ks * 4 + i;
            float4 aq = *(const float4*)&s_aT[kk][qh * 4];
            float4 vv = *(const float4*)&s_v[kk][vh * 4];
            const float ar[4] = {aq.x, aq.y, aq.z, aq.w};
            const float vc[4] = {vv.x, vv.y, vv.z, vv.w};
#pragma unroll
            for (int r = 0; r < 4; r++)
#pragma unroll
                for (int c = 0; c < 4; c++)
                    acc[r][c] = __builtin_fmaf(ar[r], vc[c], acc[r][c]);
        }
    }

#pragma unroll
    for (int r = 0; r < 4; r++)
        *(float4*)&s_red[ks][qh * 4 + r][vh * 4] =
            make_float4(acc[r][0], acc[r][1], acc[r][2], acc[r][3]);
    __syncthreads();

    if (t < 128) {   // epilogue: sum 8 k-slices, normalize, float4 store
        const int q = t >> 3, v4 = (t & 7) * 4;
        float4 o = {0.f, 0.f, 0.f, 0.f};
#pragma unroll
        for (int s = 0; s < 8; s++) {
            float4 r = *(const float4*)&s_red[s][q][v4];
            o.x += r.x; o.y += r.y; o.z += r.z; o.w += r.w;
        }
        const float inv = s_inv[q];
        o.x *= inv; o.y *= inv; o.z *= inv; o.w *= inv;
        *(float4*)(out + (size_t)(b * QN + q0 + q) * DIN + v0 + v4) = o;
    }
}

extern "C" void kernel_launch(void* const* d_in, const int* in_sizes, int n_in,
                              void* d_out, int out_size, void* d_ws, size_t ws_size,
                              hipStream_t stream) {
    const float* queries    = (const float*)d_in[0];
    const float* keys       = (const float*)d_in[1];
    const float* values     = (const float*)d_in[2];
    const int*   valid_lens = (const int*)d_in[3];
    const float* W_q        = (const float*)d_in[4];
    const float* W_k        = (const float*)d_in[5];
    const float* w_v        = (const float*)d_in[6];
    float* out = (float*)d_out;

    float* Eq      = (float*)d_ws;                    // [B*QN][HD]     512 KB
    float* EkT4    = Eq + (size_t)BQ * QN * HD;       // [B][32][KN][4]   2 MB
    float* attn    = EkT4 + (size_t)BQ * HD * KN;     // [B*QN][KN]       4 MB
    float* partial = attn + (size_t)BQ * QN * KN;     // [B*QN][8]       32 KB

    proj_kernel<<<(BQ * QN + BQ * KN) / 16, 256, 0, stream>>>(queries, keys, W_q, W_k, Eq, EkT4);
    score_kernel<<<BQ * (QN / 8) * 8, 256, 0, stream>>>(Eq, EkT4, valid_lens, w_v, attn, partial);
    av_kernel<<<BQ * 16 * 8, 256, 0, stream>>>(attn, partial, values, valid_lens, out);
}